// Round 1
// baseline (171.475 us; speedup 1.0000x reference)
//
#include <hip/hip_runtime.h>

#define NQ 10
#define QD 6
#define DIN 512
#define DOUT 64

// Precompute cos/sin of the (batch-uniform) trainable RY half-angles into ws.
__global__ __launch_bounds__(64) void dqc_precompute(const float* __restrict__ qw,
                                                     float2* __restrict__ cs) {
    const int t = threadIdx.x;
    if (t < QD * NQ) {
        float s, c;
        sincosf(qw[t] * 0.5f, &s, &c);
        cs[t] = make_float2(c, s);
    }
}

// One wave (64 lanes) simulates one sample. State: 1024 fp32 amplitudes,
// idx = (lane<<4) | r  (wire w -> bit 9-w; wires 0..5 = lane bits 5..0,
// wires 6..9 = register bits 3..0).
__global__ __launch_bounds__(256) void dqc_main(
    const float* __restrict__ x,
    const float* __restrict__ W1,
    const float* __restrict__ b1,
    const float2* __restrict__ cs,
    const float* __restrict__ W2,
    const float* __restrict__ b2,
    float* __restrict__ out,
    const int B)
{
    const int lane = threadIdx.x & 63;
    const int b = blockIdx.x * 4 + (threadIdx.x >> 6);
    if (b >= B) return;

    // ---------- front-end: dot = x[b,:] @ W1 ; theta/2 = tanh(dot+b1)*pi/4 ----------
    float xr[8];
    {
        const float4* xp = (const float4*)(x + (size_t)b * DIN + lane * 8);
        const float4 v0 = xp[0], v1 = xp[1];
        xr[0]=v0.x; xr[1]=v0.y; xr[2]=v0.z; xr[3]=v0.w;
        xr[4]=v1.x; xr[5]=v1.y; xr[6]=v1.z; xr[7]=v1.w;
    }
    float dot[NQ];
    #pragma unroll
    for (int w = 0; w < NQ; ++w) dot[w] = 0.f;
    {
        // lane handles W1 rows [8*lane, 8*lane+8); each row is 10 floats = 5 float2
        const float2* wp = (const float2*)(W1 + (size_t)lane * 8 * NQ);
        #pragma unroll
        for (int j = 0; j < 8; ++j) {
            const float2 r0 = wp[j*5+0], r1 = wp[j*5+1], r2 = wp[j*5+2],
                         r3 = wp[j*5+3], r4 = wp[j*5+4];
            dot[0] = fmaf(xr[j], r0.x, dot[0]);
            dot[1] = fmaf(xr[j], r0.y, dot[1]);
            dot[2] = fmaf(xr[j], r1.x, dot[2]);
            dot[3] = fmaf(xr[j], r1.y, dot[3]);
            dot[4] = fmaf(xr[j], r2.x, dot[4]);
            dot[5] = fmaf(xr[j], r2.y, dot[5]);
            dot[6] = fmaf(xr[j], r3.x, dot[6]);
            dot[7] = fmaf(xr[j], r3.y, dot[7]);
            dot[8] = fmaf(xr[j], r4.x, dot[8]);
            dot[9] = fmaf(xr[j], r4.y, dot[9]);
        }
    }
    #pragma unroll
    for (int w = 0; w < NQ; ++w) {
        #pragma unroll
        for (int m = 32; m >= 1; m >>= 1) dot[w] += __shfl_xor(dot[w], m, 64);
    }

    // RY(theta) on |+>: u = [(c-s)/sqrt2, (c+s)/sqrt2], c/s of theta/2
    float u0[NQ], u1[NQ];
    #pragma unroll
    for (int w = 0; w < NQ; ++w) {
        const float th2 = tanhf(dot[w] + b1[w]) * 0.78539816339744830962f; // pi/4
        float s, c;
        sincosf(th2, &s, &c);
        const float inv_sqrt2 = 0.70710678118654752440f;
        u0[w] = (c - s) * inv_sqrt2;
        u1[w] = (c + s) * inv_sqrt2;
    }

    // ---------- initial product state ----------
    float a[16];
    {
        float lf = 1.f;
        #pragma unroll
        for (int w = 0; w < 6; ++w)
            lf *= ((lane >> (5 - w)) & 1) ? u1[w] : u0[w];
        #pragma unroll
        for (int r = 0; r < 16; ++r) {
            float g = (((r >> 3) & 1) ? u1[6] : u0[6]);
            g *= (((r >> 2) & 1) ? u1[7] : u0[7]);
            g *= (((r >> 1) & 1) ? u1[8] : u0[8]);
            g *= ((r & 1) ? u1[9] : u0[9]);
            a[r] = lf * g;
        }
    }

    // ---------- 6 x (brickwall CNOT + RY layer) ----------
    #pragma unroll 1   // keep code resident in I-cache; body ~650 instrs
    for (int k = 0; k < QD; ++k) {
        // even CNOTs: (0,1),(2,3),(4,5) lane-lane; (6,7),(8,9) register-register
        {   const bool cb = (lane & 32) != 0;                   // (0,1) tgt mask 16
            #pragma unroll
            for (int r = 0; r < 16; ++r) { const float v = __shfl_xor(a[r], 16, 64); a[r] = cb ? v : a[r]; }
        }
        {   const bool cb = (lane & 8) != 0;                    // (2,3) tgt mask 4
            #pragma unroll
            for (int r = 0; r < 16; ++r) { const float v = __shfl_xor(a[r], 4, 64); a[r] = cb ? v : a[r]; }
        }
        {   const bool cb = (lane & 2) != 0;                    // (4,5) tgt mask 1
            #pragma unroll
            for (int r = 0; r < 16; ++r) { const float v = __shfl_xor(a[r], 1, 64); a[r] = cb ? v : a[r]; }
        }
        {   // (6,7): ctrl reg bit3, tgt reg bit2 -> swap a[r]<->a[r|4], r in {8,9,10,11}
            float t;
            t=a[8];  a[8]=a[12];  a[12]=t;
            t=a[9];  a[9]=a[13];  a[13]=t;
            t=a[10]; a[10]=a[14]; a[14]=t;
            t=a[11]; a[11]=a[15]; a[15]=t;
        }
        {   // (8,9): ctrl reg bit1, tgt reg bit0 -> swap a[r]<->a[r|1], r in {2,6,10,14}
            float t;
            t=a[2];  a[2]=a[3];   a[3]=t;
            t=a[6];  a[6]=a[7];   a[7]=t;
            t=a[10]; a[10]=a[11]; a[11]=t;
            t=a[14]; a[14]=a[15]; a[15]=t;
        }
        // odd CNOTs: (1,2),(3,4) lane-lane; (5,6) mixed; (7,8) register-register
        {   const bool cb = (lane & 16) != 0;                   // (1,2) tgt mask 8
            #pragma unroll
            for (int r = 0; r < 16; ++r) { const float v = __shfl_xor(a[r], 8, 64); a[r] = cb ? v : a[r]; }
        }
        {   const bool cb = (lane & 4) != 0;                    // (3,4) tgt mask 2
            #pragma unroll
            for (int r = 0; r < 16; ++r) { const float v = __shfl_xor(a[r], 2, 64); a[r] = cb ? v : a[r]; }
        }
        {   // (5,6): ctrl lane bit0, tgt reg bit3 -> lanes with bit0: swap a[r]<->a[r|8]
            const bool cb = (lane & 1) != 0;
            #pragma unroll
            for (int r = 0; r < 8; ++r) {
                const float lo = a[r], hi = a[r + 8];
                a[r]     = cb ? hi : lo;
                a[r + 8] = cb ? lo : hi;
            }
        }
        {   // (7,8): ctrl reg bit2, tgt reg bit1 -> swap a[r]<->a[r|2], r in {4,5,12,13}
            float t;
            t=a[4];  a[4]=a[6];   a[6]=t;
            t=a[5];  a[5]=a[7];   a[7]=t;
            t=a[12]; a[12]=a[14]; a[14]=t;
            t=a[13]; a[13]=a[15]; a[15]=t;
        }
        // RY layer: wires 0..5 cross-lane, wires 6..9 in-register
        #pragma unroll
        for (int w = 0; w < 6; ++w) {
            const float2 v = cs[k * NQ + w];     // wave-uniform -> s_load
            const int M = 1 << (5 - w);
            const float ss = (lane & M) ? v.y : -v.y;
            #pragma unroll
            for (int r = 0; r < 16; ++r) {
                const float p = __shfl_xor(a[r], M, 64);
                a[r] = fmaf(v.x, a[r], ss * p);
            }
        }
        #pragma unroll
        for (int w = 6; w < NQ; ++w) {
            const float2 v = cs[k * NQ + w];
            const int q = 9 - w;
            #pragma unroll
            for (int r = 0; r < 16; ++r) {
                if (!((r >> q) & 1)) {
                    const int rp = r | (1 << q);
                    const float a0 = a[r], a1 = a[rp];
                    a[r]  = fmaf(v.x, a0, -(v.y * a1));
                    a[rp] = fmaf(v.x, a1,  (v.y * a0));
                }
            }
        }
    }

    // ---------- expvals <Z_w> + output GEMM (lane = output column) ----------
    float p2[16], tot = 0.f;
    #pragma unroll
    for (int r = 0; r < 16; ++r) { p2[r] = a[r] * a[r]; tot += p2[r]; }
    float e[NQ];
    #pragma unroll
    for (int w = 0; w < 6; ++w)
        e[w] = ((lane >> (5 - w)) & 1) ? -tot : tot;
    #pragma unroll
    for (int w = 6; w < NQ; ++w) {
        const int q = 9 - w;
        float s = 0.f;
        #pragma unroll
        for (int r = 0; r < 16; ++r) s += ((r >> q) & 1) ? -p2[r] : p2[r];
        e[w] = s;
    }
    #pragma unroll
    for (int w = 0; w < NQ; ++w) {
        #pragma unroll
        for (int m = 32; m >= 1; m >>= 1) e[w] += __shfl_xor(e[w], m, 64);
    }
    float o = b2[lane];
    #pragma unroll
    for (int w = 0; w < NQ; ++w) o = fmaf(e[w], W2[w * DOUT + lane], o);
    out[(size_t)b * DOUT + lane] = o;
}

extern "C" void kernel_launch(void* const* d_in, const int* in_sizes, int n_in,
                              void* d_out, int out_size, void* d_ws, size_t ws_size,
                              hipStream_t stream) {
    const float* x  = (const float*)d_in[0];
    const float* W1 = (const float*)d_in[1];
    const float* b1 = (const float*)d_in[2];
    const float* qw = (const float*)d_in[3];
    const float* W2 = (const float*)d_in[4];
    const float* b2 = (const float*)d_in[5];
    float* out = (float*)d_out;
    float2* cs = (float2*)d_ws;   // 60 float2 = 480 B

    const int B = in_sizes[0] / DIN;
    dqc_precompute<<<1, 64, 0, stream>>>(qw, cs);
    dqc_main<<<(B + 3) / 4, 256, 0, stream>>>(x, W1, b1, cs, W2, b2, out, B);
}

// Round 2
// 120.990 us; speedup vs baseline: 1.4173x; 1.4173x over previous
//
#include <hip/hip_runtime.h>

#define NQ 10
#define QD 6
#define DIN 512
#define DOUT 64

// ---- cross-lane helpers ------------------------------------------------
// xor-shuffle within 16-lane groups. Masks 1,2 -> DPP quad_perm (VALU pipe),
// masks 4,8 -> ds_swizzle BitMode (LDS pipe).
template <int CTRL>
__device__ __forceinline__ float dppf(float v) {
    return __int_as_float(__builtin_amdgcn_mov_dpp(__float_as_int(v), CTRL, 0xF, 0xF, true));
}
template <int M>
__device__ __forceinline__ float sx(float v) {
    if constexpr (M == 1)      return dppf<0xB1>(v);  // quad_perm [1,0,3,2]
    else if constexpr (M == 2) return dppf<0x4E>(v);  // quad_perm [2,3,0,1]
    else return __int_as_float(__builtin_amdgcn_ds_swizzle(__float_as_int(v), (M << 10) | 0x1F));
}
__device__ __forceinline__ float red16(float v) {
    v += sx<8>(v); v += sx<4>(v); v += sx<2>(v); v += sx<1>(v);
    return v;  // all 16 lanes hold the group sum
}

// One 16-lane group simulates one sample: 4 samples/wave, 16/block.
// Amplitude index: idx = (lane16 << 6) | r  (wire w -> idx bit 9-w).
// Wires 0..3 = lane16 bits 3..0 (cross-lane); wires 4..9 = r bits 5..0 (in-register).
__global__ __launch_bounds__(256) void dqc_main(
    const float* __restrict__ x,
    const float* __restrict__ W1,
    const float* __restrict__ b1,
    const float* __restrict__ qw,
    const float* __restrict__ W2,
    const float* __restrict__ b2,
    float* __restrict__ out,
    const int B)
{
    __shared__ __align__(16) float csl[2 * QD * NQ];  // interleaved c,s per gate

    const int tid = threadIdx.x;
    if (tid < QD * NQ) {
        float s, c;
        sincosf(qw[tid] * 0.5f, &s, &c);
        csl[2 * tid] = c; csl[2 * tid + 1] = s;
    }

    const int lane16 = tid & 15;
    const int b  = (blockIdx.x * 256 + tid) >> 4;
    const int bb = (b < B) ? b : (B - 1);   // clamp for loads; store guarded

    // ---------- front-end: dot = x[b,:] @ W1 ----------
    float xr[32];
    {
        const float4* xp = (const float4*)(x + (size_t)bb * DIN + lane16 * 32);
        #pragma unroll
        for (int i = 0; i < 8; ++i) {
            const float4 v = xp[i];
            xr[4*i] = v.x; xr[4*i+1] = v.y; xr[4*i+2] = v.z; xr[4*i+3] = v.w;
        }
    }
    float dot[NQ];
    #pragma unroll
    for (int w = 0; w < NQ; ++w) dot[w] = 0.f;
    {
        // lane handles W1 rows [32*lane16, +32); 2 rows = 20 floats = 5 float4
        const float4* wp = (const float4*)(W1 + (size_t)lane16 * 32 * NQ);
        #pragma unroll
        for (int j = 0; j < 16; ++j) {
            const float4 f0 = wp[5*j], f1 = wp[5*j+1], f2 = wp[5*j+2],
                         f3 = wp[5*j+3], f4 = wp[5*j+4];
            const float xa = xr[2*j], xb = xr[2*j+1];
            dot[0]=fmaf(xa,f0.x,dot[0]); dot[1]=fmaf(xa,f0.y,dot[1]);
            dot[2]=fmaf(xa,f0.z,dot[2]); dot[3]=fmaf(xa,f0.w,dot[3]);
            dot[4]=fmaf(xa,f1.x,dot[4]); dot[5]=fmaf(xa,f1.y,dot[5]);
            dot[6]=fmaf(xa,f1.z,dot[6]); dot[7]=fmaf(xa,f1.w,dot[7]);
            dot[8]=fmaf(xa,f2.x,dot[8]); dot[9]=fmaf(xa,f2.y,dot[9]);
            dot[0]=fmaf(xb,f2.z,dot[0]); dot[1]=fmaf(xb,f2.w,dot[1]);
            dot[2]=fmaf(xb,f3.x,dot[2]); dot[3]=fmaf(xb,f3.y,dot[3]);
            dot[4]=fmaf(xb,f3.z,dot[4]); dot[5]=fmaf(xb,f3.w,dot[5]);
            dot[6]=fmaf(xb,f4.x,dot[6]); dot[7]=fmaf(xb,f4.y,dot[7]);
            dot[8]=fmaf(xb,f4.z,dot[8]); dot[9]=fmaf(xb,f4.w,dot[9]);
        }
    }
    #pragma unroll
    for (int w = 0; w < NQ; ++w) dot[w] = red16(dot[w]);

    // RY(theta) on |+>: u = [(c-s), (c+s)] / sqrt2, from theta/2
    float u0[NQ], u1[NQ];
    #pragma unroll
    for (int w = 0; w < NQ; ++w) {
        const float th2 = tanhf(dot[w] + b1[w]) * 0.78539816339744830962f;  // pi/4
        float s, c;
        sincosf(th2, &s, &c);
        const float isq2 = 0.70710678118654752440f;
        u0[w] = (c - s) * isq2;
        u1[w] = (c + s) * isq2;
    }

    // ---------- initial product state (64 amplitudes/lane) ----------
    float a[64];
    {
        float lf = ((lane16 & 8) ? u1[0] : u0[0]);
        lf *= ((lane16 & 4) ? u1[1] : u0[1]);
        lf *= ((lane16 & 2) ? u1[2] : u0[2]);
        lf *= ((lane16 & 1) ? u1[3] : u0[3]);
        a[0] = lf;
        #pragma unroll
        for (int w = 4; w < NQ; ++w) {
            const int n = 1 << (w - 4);
            #pragma unroll
            for (int i = n - 1; i >= 0; --i) {
                const float base = a[i];
                a[2*i]   = base * u0[w];
                a[2*i+1] = base * u1[w];
            }
        }
    }

    __syncthreads();  // csl ready (all threads reach this — no early return)

    // ---------- 6 x (brickwall CNOT + RY layer) ----------
    #pragma unroll 1
    for (int k = 0; k < QD; ++k) {
        const float4* cp = (const float4*)(csl + k * 2 * NQ);
        const float4 q0 = cp[0], q1 = cp[1], q2 = cp[2], q3 = cp[3], q4 = cp[4];
        const float C0=q0.x,S0=q0.y, C1=q0.z,S1=q0.w;
        const float C2=q1.x,S2=q1.y, C3=q1.z,S3=q1.w;
        const float C4=q2.x,S4=q2.y, C5=q2.z,S5=q2.w;
        const float C6=q3.x,S6=q3.y, C7=q3.z,S7=q3.w;
        const float C8=q4.x,S8=q4.y, C9=q4.z,S9=q4.w;

        // --- even CNOTs ---
        {   // (0,1): ctrl lane bit3, tgt lane mask 4 (ds_swizzle)
            const bool cb = (lane16 & 8) != 0;
            #pragma unroll
            for (int r = 0; r < 64; ++r) { const float v = sx<4>(a[r]); a[r] = cb ? v : a[r]; }
        }
        {   // (2,3): ctrl lane bit1, tgt lane mask 1 (DPP)
            const bool cb = (lane16 & 2) != 0;
            #pragma unroll
            for (int r = 0; r < 64; ++r) { const float v = sx<1>(a[r]); a[r] = cb ? v : a[r]; }
        }
        {   // (4,5): ctrl r bit5, tgt r bit4 — register permutation
            #pragma unroll
            for (int i = 0; i < 16; ++i) { const float t = a[32+i]; a[32+i] = a[48+i]; a[48+i] = t; }
        }
        {   // (6,7): ctrl r bit3, tgt r bit2
            #pragma unroll
            for (int j = 0; j < 4; ++j)
                #pragma unroll
                for (int i = 0; i < 4; ++i) { const int r = 16*j + 8 + i; const float t = a[r]; a[r] = a[r+4]; a[r+4] = t; }
        }
        {   // (8,9): ctrl r bit1, tgt r bit0
            #pragma unroll
            for (int r = 2; r < 64; r += 4) { const float t = a[r]; a[r] = a[r+1]; a[r+1] = t; }
        }
        // --- odd CNOTs ---
        {   // (1,2): ctrl lane bit2, tgt lane mask 2 (DPP)
            const bool cb = (lane16 & 4) != 0;
            #pragma unroll
            for (int r = 0; r < 64; ++r) { const float v = sx<2>(a[r]); a[r] = cb ? v : a[r]; }
        }
        {   // (5,6): ctrl r bit4, tgt r bit3
            #pragma unroll
            for (int j = 0; j < 2; ++j)
                #pragma unroll
                for (int i = 0; i < 8; ++i) { const int r = 32*j + 16 + i; const float t = a[r]; a[r] = a[r+8]; a[r+8] = t; }
        }
        {   // (7,8): ctrl r bit2, tgt r bit1
            #pragma unroll
            for (int r = 0; r < 64; r += 8) {
                float t = a[r+4]; a[r+4] = a[r+6]; a[r+6] = t;
                t = a[r+5]; a[r+5] = a[r+7]; a[r+7] = t;
            }
        }
        // --- fused CNOT(3,4) + RY(wire4): ctrl lane bit0, pairs (r, r+32) ---
        // (applied before RY(w3); legal since RYs commute and C(3,4) precedes RY(w3))
        {
            const bool cb = (lane16 & 1) != 0;
            const float al = cb ? -S4 :  C4;
            const float be = cb ?  C4 : -S4;
            const float ga = cb ?  C4 :  S4;
            const float de = cb ?  S4 :  C4;
            #pragma unroll
            for (int r = 0; r < 32; ++r) {
                const float a0 = a[r], a1 = a[r+32];
                a[r]    = fmaf(al, a0, be * a1);
                a[r+32] = fmaf(ga, a0, de * a1);
            }
        }
        // --- RY lane wires 0..3 ---
        {   const float ss = (lane16 & 8) ? S0 : -S0;
            #pragma unroll
            for (int r = 0; r < 64; ++r) { const float p = sx<8>(a[r]); a[r] = fmaf(C0, a[r], ss * p); }
        }
        {   const float ss = (lane16 & 4) ? S1 : -S1;
            #pragma unroll
            for (int r = 0; r < 64; ++r) { const float p = sx<4>(a[r]); a[r] = fmaf(C1, a[r], ss * p); }
        }
        {   const float ss = (lane16 & 2) ? S2 : -S2;
            #pragma unroll
            for (int r = 0; r < 64; ++r) { const float p = sx<2>(a[r]); a[r] = fmaf(C2, a[r], ss * p); }
        }
        {   const float ss = (lane16 & 1) ? S3 : -S3;
            #pragma unroll
            for (int r = 0; r < 64; ++r) { const float p = sx<1>(a[r]); a[r] = fmaf(C3, a[r], ss * p); }
        }
        // --- RY register wires 5..9 ---
        {   // w5: D=16
            #pragma unroll
            for (int r = 0; r < 64; ++r) if (!(r & 16)) {
                const float a0 = a[r], a1 = a[r|16];
                a[r]    = fmaf(C5, a0, -(S5 * a1));
                a[r|16] = fmaf(C5, a1,  S5 * a0);
            }
        }
        {   // w6: D=8
            #pragma unroll
            for (int r = 0; r < 64; ++r) if (!(r & 8)) {
                const float a0 = a[r], a1 = a[r|8];
                a[r]   = fmaf(C6, a0, -(S6 * a1));
                a[r|8] = fmaf(C6, a1,  S6 * a0);
            }
        }
        {   // w7: D=4
            #pragma unroll
            for (int r = 0; r < 64; ++r) if (!(r & 4)) {
                const float a0 = a[r], a1 = a[r|4];
                a[r]   = fmaf(C7, a0, -(S7 * a1));
                a[r|4] = fmaf(C7, a1,  S7 * a0);
            }
        }
        {   // w8: D=2
            #pragma unroll
            for (int r = 0; r < 64; ++r) if (!(r & 2)) {
                const float a0 = a[r], a1 = a[r|2];
                a[r]   = fmaf(C8, a0, -(S8 * a1));
                a[r|2] = fmaf(C8, a1,  S8 * a0);
            }
        }
        {   // w9: D=1
            #pragma unroll
            for (int r = 0; r < 64; ++r) if (!(r & 1)) {
                const float a0 = a[r], a1 = a[r|1];
                a[r]   = fmaf(C9, a0, -(S9 * a1));
                a[r|1] = fmaf(C9, a1,  S9 * a0);
            }
        }
    }

    // ---------- expvals <Z_w> ----------
    float tot = 0.f, t4 = 0.f, t5 = 0.f, t6 = 0.f, t7 = 0.f, t8 = 0.f, t9 = 0.f;
    #pragma unroll
    for (int r = 0; r < 64; ++r) {
        const float p = a[r] * a[r];
        tot += p;
        if (r & 32) t4 += p;
        if (r & 16) t5 += p;
        if (r & 8)  t6 += p;
        if (r & 4)  t7 += p;
        if (r & 2)  t8 += p;
        if (r & 1)  t9 += p;
    }
    float e[NQ];
    e[0] = (lane16 & 8) ? -tot : tot;
    e[1] = (lane16 & 4) ? -tot : tot;
    e[2] = (lane16 & 2) ? -tot : tot;
    e[3] = (lane16 & 1) ? -tot : tot;
    e[4] = tot - 2.f * t4;
    e[5] = tot - 2.f * t5;
    e[6] = tot - 2.f * t6;
    e[7] = tot - 2.f * t7;
    e[8] = tot - 2.f * t8;
    e[9] = tot - 2.f * t9;
    #pragma unroll
    for (int w = 0; w < NQ; ++w) e[w] = red16(e[w]);

    // ---------- output GEMM: lane covers cols [4*lane16, +4) ----------
    if (b < B) {
        float4 o = ((const float4*)b2)[lane16];
        #pragma unroll
        for (int w = 0; w < NQ; ++w) {
            const float4 wv = ((const float4*)(W2 + w * DOUT))[lane16];
            o.x = fmaf(e[w], wv.x, o.x);
            o.y = fmaf(e[w], wv.y, o.y);
            o.z = fmaf(e[w], wv.z, o.z);
            o.w = fmaf(e[w], wv.w, o.w);
        }
        ((float4*)(out + (size_t)b * DOUT))[lane16] = o;
    }
}

extern "C" void kernel_launch(void* const* d_in, const int* in_sizes, int n_in,
                              void* d_out, int out_size, void* d_ws, size_t ws_size,
                              hipStream_t stream) {
    const float* x  = (const float*)d_in[0];
    const float* W1 = (const float*)d_in[1];
    const float* b1 = (const float*)d_in[2];
    const float* qw = (const float*)d_in[3];
    const float* W2 = (const float*)d_in[4];
    const float* b2 = (const float*)d_in[5];
    float* out = (float*)d_out;

    const int B = in_sizes[0] / DIN;
    const int blocks = (B + 15) / 16;  // 16 samples per 256-thread block
    dqc_main<<<blocks, 256, 0, stream>>>(x, W1, b1, qw, W2, b2, out, B);
}

// Round 3
// 115.587 us; speedup vs baseline: 1.4835x; 1.0467x over previous
//
#include <hip/hip_runtime.h>

#define NQ 10
#define QD 6
#define DIN 512
#define DOUT 64

typedef float v2f __attribute__((ext_vector_type(2)));

__device__ __forceinline__ v2f sp(float s) { v2f r; r.x = s; r.y = s; return r; }
__device__ __forceinline__ v2f mk(float a, float b) { v2f r; r.x = a; r.y = b; return r; }
#define PKF(a, b, c) __builtin_elementwise_fma(a, b, c)

// ---- cross-lane helpers (within 16-lane groups) ------------------------
template <int CTRL>
__device__ __forceinline__ float dppf(float v) {
    return __int_as_float(__builtin_amdgcn_mov_dpp(__float_as_int(v), CTRL, 0xF, 0xF, true));
}
template <int M>
__device__ __forceinline__ float sx(float v) {
    if constexpr (M == 1)      return dppf<0xB1>(v);  // quad_perm [1,0,3,2]
    else if constexpr (M == 2) return dppf<0x4E>(v);  // quad_perm [2,3,0,1]
    else return __int_as_float(__builtin_amdgcn_ds_swizzle(__float_as_int(v), (M << 10) | 0x1F));
}
template <int M>
__device__ __forceinline__ v2f sx2(v2f v) { return mk(sx<M>(v.x), sx<M>(v.y)); }
__device__ __forceinline__ float red16(float v) {
    v += sx<8>(v); v += sx<4>(v); v += sx<2>(v); v += sx<1>(v);
    return v;
}

// One 16-lane group = one sample. Amp idx = (lane16<<6)|r, r = 2m|comp.
// Wires 0..3 = lane16 bits 3..0; wires 4..9 = r bits 5..0 (m4..m0, comp).
// All CNOTs are fused into RY coefficient tables:
//   pre-CNOT+RY : (alpha,beta) = cbit ? ( g, C) : (C, g),  g = tbit ? S : -S
//   RY+post-CNOT: (alpha,beta) = cbit ? (-g, C) : (C, g)
// Layer order: [w0, w2+preC12, w4+preC34, w6+preC56, w8+preC78] then
//              [w1+postC01, w3+postC23, w5+postC45, w7+postC67, w9+postC89]
// which equals O_k * R_k * E_{k+1}; E_0 is folded into the initial state.
__global__ __launch_bounds__(256, 2) void dqc_main(
    const float* __restrict__ x,
    const float* __restrict__ W1,
    const float* __restrict__ b1,
    const float* __restrict__ qw,
    const float* __restrict__ W2,
    const float* __restrict__ b2,
    float* __restrict__ out,
    const int B)
{
    __shared__ __align__(16) float csl[2 * QD * NQ];

    const int tid = threadIdx.x;
    if (tid < QD * NQ) {
        float s, c;
        sincosf(qw[tid] * 0.5f, &s, &c);
        csl[2 * tid] = c; csl[2 * tid + 1] = s;
    }

    const int lane16 = tid & 15;
    const int b  = (blockIdx.x * 256 + tid) >> 4;
    const int bb = (b < B) ? b : (B - 1);

    // ---------- front-end: dot = x[b,:] @ W1 ----------
    float xr[32];
    {
        const float4* xp = (const float4*)(x + (size_t)bb * DIN + lane16 * 32);
        #pragma unroll
        for (int i = 0; i < 8; ++i) {
            const float4 v = xp[i];
            xr[4*i] = v.x; xr[4*i+1] = v.y; xr[4*i+2] = v.z; xr[4*i+3] = v.w;
        }
    }
    float dot[NQ];
    #pragma unroll
    for (int w = 0; w < NQ; ++w) dot[w] = 0.f;
    {
        const float4* wp = (const float4*)(W1 + (size_t)lane16 * 32 * NQ);
        #pragma unroll
        for (int j = 0; j < 16; ++j) {
            const float4 f0 = wp[5*j], f1 = wp[5*j+1], f2 = wp[5*j+2],
                         f3 = wp[5*j+3], f4 = wp[5*j+4];
            const float xa = xr[2*j], xb = xr[2*j+1];
            dot[0]=fmaf(xa,f0.x,dot[0]); dot[1]=fmaf(xa,f0.y,dot[1]);
            dot[2]=fmaf(xa,f0.z,dot[2]); dot[3]=fmaf(xa,f0.w,dot[3]);
            dot[4]=fmaf(xa,f1.x,dot[4]); dot[5]=fmaf(xa,f1.y,dot[5]);
            dot[6]=fmaf(xa,f1.z,dot[6]); dot[7]=fmaf(xa,f1.w,dot[7]);
            dot[8]=fmaf(xa,f2.x,dot[8]); dot[9]=fmaf(xa,f2.y,dot[9]);
            dot[0]=fmaf(xb,f2.z,dot[0]); dot[1]=fmaf(xb,f2.w,dot[1]);
            dot[2]=fmaf(xb,f3.x,dot[2]); dot[3]=fmaf(xb,f3.y,dot[3]);
            dot[4]=fmaf(xb,f3.z,dot[4]); dot[5]=fmaf(xb,f3.w,dot[5]);
            dot[6]=fmaf(xb,f4.x,dot[6]); dot[7]=fmaf(xb,f4.y,dot[7]);
            dot[8]=fmaf(xb,f4.z,dot[8]); dot[9]=fmaf(xb,f4.w,dot[9]);
        }
    }
    #pragma unroll
    for (int w = 0; w < NQ; ++w) dot[w] = red16(dot[w]);

    float u0[NQ], u1[NQ];
    #pragma unroll
    for (int w = 0; w < NQ; ++w) {
        const float th2 = tanhf(dot[w] + b1[w]) * 0.78539816339744830962f;  // pi/4
        float s, c;
        sincosf(th2, &s, &c);
        const float isq2 = 0.70710678118654752440f;
        u0[w] = (c - s) * isq2;
        u1[w] = (c + s) * isq2;
    }

    // ---------- initial product state with E_0 folded (bit relabel) ----------
    // w1 <- b2^b3, w3 <- b0^b1 (lane); w5 <- m3^m4, w7 <- m1^m2, w9 <- comp^m0
    v2f A[32];
    {
        float lf = ((lane16 & 8) ? u1[0] : u0[0]);
        lf *= ((((lane16 >> 2) ^ (lane16 >> 3)) & 1) ? u1[1] : u0[1]);
        lf *= ((lane16 & 2) ? u1[2] : u0[2]);
        lf *= (((lane16 ^ (lane16 >> 1)) & 1) ? u1[3] : u0[3]);
        #pragma unroll
        for (int m = 0; m < 32; ++m) {
            float f = ((m & 16) ? u1[4] : u0[4]);
            f *= ((((m >> 3) ^ (m >> 4)) & 1) ? u1[5] : u0[5]);
            f *= ((m & 4) ? u1[6] : u0[6]);
            f *= ((((m >> 1) ^ (m >> 2)) & 1) ? u1[7] : u0[7]);
            f *= ((m & 1) ? u1[8] : u0[8]);
            f *= lf;
            A[m] = (m & 1) ? mk(f * u1[9], f * u0[9]) : mk(f * u0[9], f * u1[9]);
        }
    }

    __syncthreads();  // csl ready

    // ---------- 6 fused layers ----------
    #pragma unroll 1
    for (int k = 0; k < QD; ++k) {
        const float4* cp = (const float4*)(csl + k * 2 * NQ);
        const float4 g0 = cp[0], g1 = cp[1], g2 = cp[2], g3 = cp[3], g4 = cp[4];
        const float C0=g0.x,S0=g0.y, C1=g0.z,S1=g0.w;
        const float C2=g1.x,S2=g1.y, C3=g1.z,S3=g1.w;
        const float C4=g2.x,S4=g2.y, C5=g2.z,S5=g2.w;
        const float C6=g3.x,S6=g3.y, C7=g3.z,S7=g3.w;
        const float C8=g4.x,S8=g4.y, C9=g4.z,S9=g4.w;
        const bool fuse = (k < QD - 1);

        // ==== even phase ====
        {   // w0 plain: t = lane b3 (sx<8>)
            const float g = (lane16 & 8) ? S0 : -S0;
            const v2f al = sp(C0), be = sp(g);
            #pragma unroll
            for (int m = 0; m < 32; ++m) { const v2f p = sx2<8>(A[m]); A[m] = PKF(al, A[m], be * p); }
        }
        {   // w2 + pre C(1,2): t = lane b1 (DPP), c = lane b2
            const float g = (lane16 & 2) ? S2 : -S2;
            const bool cb = (lane16 & 4) != 0;
            const v2f al = sp(cb ? g : C2), be = sp(cb ? C2 : g);
            #pragma unroll
            for (int m = 0; m < 32; ++m) { const v2f p = sx2<2>(A[m]); A[m] = PKF(al, A[m], be * p); }
        }
        {   // w4 + pre C(3,4): t = m4 (pairs m, m+16), c = lane b0
            const bool cb = (lane16 & 1) != 0;
            const v2f a0 = sp(cb ? -S4 : C4), b0 = sp(cb ? C4 : -S4);
            const v2f a1 = sp(cb ?  S4 : C4), b1v = sp(cb ? C4 :  S4);
            #pragma unroll
            for (int m = 0; m < 16; ++m) {
                const v2f lo = A[m], hi = A[m + 16];
                A[m]      = PKF(a0, lo, b0 * hi);
                A[m + 16] = PKF(a1, hi, b1v * lo);
            }
        }
        {   // w6 + pre C(5,6): t = m2 (pairs m, m+4), c = m3 (compile-time)
            #pragma unroll
            for (int m = 0; m < 32; ++m) {
                if (m & 4) continue;
                const v2f lo = A[m], hi = A[m + 4];
                if ((m >> 3) & 1) {
                    A[m]     = PKF(sp(-S6), lo, sp(C6) * hi);
                    A[m + 4] = PKF(sp( S6), hi, sp(C6) * lo);
                } else {
                    A[m]     = PKF(sp(C6), lo, sp(-S6) * hi);
                    A[m + 4] = PKF(sp(C6), hi, sp( S6) * lo);
                }
            }
        }
        {   // w8 + pre C(7,8): t = m0 (pairs 2q, 2q+1), c = m1 (compile-time)
            #pragma unroll
            for (int q = 0; q < 16; ++q) {
                const v2f lo = A[2*q], hi = A[2*q+1];
                if (q & 1) {
                    A[2*q]   = PKF(sp(-S8), lo, sp(C8) * hi);
                    A[2*q+1] = PKF(sp( S8), hi, sp(C8) * lo);
                } else {
                    A[2*q]   = PKF(sp(C8), lo, sp(-S8) * hi);
                    A[2*q+1] = PKF(sp(C8), hi, sp( S8) * lo);
                }
            }
        }

        // ==== odd phase ====
        {   // w1 + post C(0,1): t = lane b2 (sx<4>), c = lane b3
            const float g = (lane16 & 4) ? S1 : -S1;
            const bool cb = fuse && ((lane16 & 8) != 0);
            const v2f al = sp(cb ? -g : C1), be = sp(cb ? C1 : g);
            #pragma unroll
            for (int m = 0; m < 32; ++m) { const v2f p = sx2<4>(A[m]); A[m] = PKF(al, A[m], be * p); }
        }
        {   // w3 + post C(2,3): t = lane b0 (DPP), c = lane b1
            const float g = (lane16 & 1) ? S3 : -S3;
            const bool cb = fuse && ((lane16 & 2) != 0);
            const v2f al = sp(cb ? -g : C3), be = sp(cb ? C3 : g);
            #pragma unroll
            for (int m = 0; m < 32; ++m) { const v2f p = sx2<1>(A[m]); A[m] = PKF(al, A[m], be * p); }
        }
        {   // w5 + post C(4,5): t = m3 (pairs m, m+8), c = m4 (compile-time bit, runtime fuse)
            const float a0c = fuse ?  S5 : C5,  b0c = fuse ? C5 : -S5;
            const float a1c = fuse ? -S5 : C5,  b1c = fuse ? C5 :  S5;
            #pragma unroll
            for (int m = 0; m < 32; ++m) {
                if (m & 8) continue;
                const v2f lo = A[m], hi = A[m + 8];
                if ((m >> 4) & 1) {
                    A[m]     = PKF(sp(a0c), lo, sp(b0c) * hi);
                    A[m + 8] = PKF(sp(a1c), hi, sp(b1c) * lo);
                } else {
                    A[m]     = PKF(sp(C5), lo, sp(-S5) * hi);
                    A[m + 8] = PKF(sp(C5), hi, sp( S5) * lo);
                }
            }
        }
        {   // w7 + post C(6,7): t = m1 (pairs m, m+2), c = m2
            const float a0c = fuse ?  S7 : C7,  b0c = fuse ? C7 : -S7;
            const float a1c = fuse ? -S7 : C7,  b1c = fuse ? C7 :  S7;
            #pragma unroll
            for (int m = 0; m < 32; ++m) {
                if (m & 2) continue;
                const v2f lo = A[m], hi = A[m + 2];
                if ((m >> 2) & 1) {
                    A[m]     = PKF(sp(a0c), lo, sp(b0c) * hi);
                    A[m + 2] = PKF(sp(a1c), hi, sp(b1c) * lo);
                } else {
                    A[m]     = PKF(sp(C7), lo, sp(-S7) * hi);
                    A[m + 2] = PKF(sp(C7), hi, sp( S7) * lo);
                }
            }
        }
        {   // w9 + post C(8,9): t = comp (in-register pair), c = m0
            const v2f Ae = sp(C9), Be = mk(-S9, S9);
            const v2f Ao = fuse ? mk(S9, -S9) : Ae;
            const v2f Bo = fuse ? sp(C9) : Be;
            #pragma unroll
            for (int m = 0; m < 32; ++m) {
                const v2f s = mk(A[m].y, A[m].x);
                A[m] = (m & 1) ? PKF(Ao, A[m], Bo * s) : PKF(Ae, A[m], Be * s);
            }
        }
    }

    // ---------- expvals <Z_w> ----------
    v2f tot2 = sp(0.f), q4 = sp(0.f), q5 = sp(0.f), q6 = sp(0.f), q7 = sp(0.f), q8 = sp(0.f);
    #pragma unroll
    for (int m = 0; m < 32; ++m) {
        const v2f P = A[m] * A[m];
        tot2 += P;
        if (m & 16) q4 += P;
        if (m & 8)  q5 += P;
        if (m & 4)  q6 += P;
        if (m & 2)  q7 += P;
        if (m & 1)  q8 += P;
    }
    const float tot = tot2.x + tot2.y;
    float e[NQ];
    e[0] = (lane16 & 8) ? -tot : tot;
    e[1] = (lane16 & 4) ? -tot : tot;
    e[2] = (lane16 & 2) ? -tot : tot;
    e[3] = (lane16 & 1) ? -tot : tot;
    e[4] = tot - 2.f * (q4.x + q4.y);
    e[5] = tot - 2.f * (q5.x + q5.y);
    e[6] = tot - 2.f * (q6.x + q6.y);
    e[7] = tot - 2.f * (q7.x + q7.y);
    e[8] = tot - 2.f * (q8.x + q8.y);
    e[9] = tot - 2.f * tot2.y;
    #pragma unroll
    for (int w = 0; w < NQ; ++w) e[w] = red16(e[w]);

    // ---------- output GEMM ----------
    if (b < B) {
        float4 o = ((const float4*)b2)[lane16];
        #pragma unroll
        for (int w = 0; w < NQ; ++w) {
            const float4 wv = ((const float4*)(W2 + w * DOUT))[lane16];
            o.x = fmaf(e[w], wv.x, o.x);
            o.y = fmaf(e[w], wv.y, o.y);
            o.z = fmaf(e[w], wv.z, o.z);
            o.w = fmaf(e[w], wv.w, o.w);
        }
        ((float4*)(out + (size_t)b * DOUT))[lane16] = o;
    }
}

extern "C" void kernel_launch(void* const* d_in, const int* in_sizes, int n_in,
                              void* d_out, int out_size, void* d_ws, size_t ws_size,
                              hipStream_t stream) {
    const float* x  = (const float*)d_in[0];
    const float* W1 = (const float*)d_in[1];
    const float* b1 = (const float*)d_in[2];
    const float* qw = (const float*)d_in[3];
    const float* W2 = (const float*)d_in[4];
    const float* b2 = (const float*)d_in[5];
    float* out = (float*)d_out;

    const int B = in_sizes[0] / DIN;
    const int blocks = (B + 15) / 16;
    dqc_main<<<blocks, 256, 0, stream>>>(x, W1, b1, qw, W2, b2, out, B);
}

// Round 4
// 111.647 us; speedup vs baseline: 1.5359x; 1.0353x over previous
//
#include <hip/hip_runtime.h>

#define NQ 10
#define QD 6
#define DIN 512
#define DOUT 64

typedef float v2f __attribute__((ext_vector_type(2)));

__device__ __forceinline__ v2f sp(float s) { v2f r; r.x = s; r.y = s; return r; }
__device__ __forceinline__ v2f mk(float a, float b) { v2f r; r.x = a; r.y = b; return r; }
#define PKF(a, b, c) __builtin_elementwise_fma(a, b, c)

// ---- cross-lane via DPP only (no DS ops anywhere) ----------------------
// xor-exchange within 16-lane rows:
//   xor1 = quad_perm[1,0,3,2] (0xB1)
//   xor2 = quad_perm[2,3,0,1] (0x4E)
//   xor4 = row_half_mirror (xor7, 0x141) o quad_perm[3,2,1,0] (xor3, 0x1B)
//   xor8 = row_ror:8 (0x128)  -- rotate by 8 mod 16 == xor 8
template <int CTRL>
__device__ __forceinline__ float dppf(float v) {
    return __int_as_float(__builtin_amdgcn_mov_dpp(__float_as_int(v), CTRL, 0xF, 0xF, true));
}
template <int M>
__device__ __forceinline__ float sx(float v) {
    if constexpr (M == 1)      return dppf<0xB1>(v);
    else if constexpr (M == 2) return dppf<0x4E>(v);
    else if constexpr (M == 4) return dppf<0x1B>(dppf<0x141>(v));
    else                       return dppf<0x128>(v);
}
template <int M>
__device__ __forceinline__ v2f sx2(v2f v) { return mk(sx<M>(v.x), sx<M>(v.y)); }
// rotate-based allreduce over 16-lane rows (sum broadcast to all 16 lanes)
__device__ __forceinline__ float red16(float v) {
    v += dppf<0x128>(v);   // row_ror:8
    v += dppf<0x124>(v);   // row_ror:4
    v += dppf<0x122>(v);   // row_ror:2
    v += dppf<0x121>(v);   // row_ror:1
    return v;
}

// One 16-lane group = one sample. Amp idx = (lane16<<6)|r, r = 2m|comp.
// Wires 0..3 = lane16 bits 3..0; wires 4..9 = r bits 5..0 (m4..m0, comp).
// All CNOTs fused into RY coefficient tables (see R3 derivation):
//   pre-CNOT+RY : (alpha,beta) = cbit ? ( g, C) : (C, g),  g = tbit ? S : -S
//   RY+post-CNOT: (alpha,beta) = cbit ? (-g, C) : (C, g)
// Layer = O_k * R_k * E_{k+1}; E_0 folded into initial state as bit relabel.
__global__ __launch_bounds__(256, 2) void dqc_main(
    const float* __restrict__ x,
    const float* __restrict__ W1,
    const float* __restrict__ b1,
    const float* __restrict__ qw,
    const float* __restrict__ W2,
    const float* __restrict__ b2,
    float* __restrict__ out,
    const int B)
{
    __shared__ __align__(16) float csl[2 * QD * NQ];

    const int tid = threadIdx.x;
    if (tid < QD * NQ) {
        float s, c;
        sincosf(qw[tid] * 0.5f, &s, &c);
        csl[2 * tid] = c; csl[2 * tid + 1] = s;
    }

    const int lane16 = tid & 15;
    const int b  = (blockIdx.x * 256 + tid) >> 4;
    const int bb = (b < B) ? b : (B - 1);

    // ---------- front-end: dot = x[b,:] @ W1 ----------
    float xr[32];
    {
        const float4* xp = (const float4*)(x + (size_t)bb * DIN + lane16 * 32);
        #pragma unroll
        for (int i = 0; i < 8; ++i) {
            const float4 v = xp[i];
            xr[4*i] = v.x; xr[4*i+1] = v.y; xr[4*i+2] = v.z; xr[4*i+3] = v.w;
        }
    }
    float dot[NQ];
    #pragma unroll
    for (int w = 0; w < NQ; ++w) dot[w] = 0.f;
    {
        const float4* wp = (const float4*)(W1 + (size_t)lane16 * 32 * NQ);
        #pragma unroll
        for (int j = 0; j < 16; ++j) {
            const float4 f0 = wp[5*j], f1 = wp[5*j+1], f2 = wp[5*j+2],
                         f3 = wp[5*j+3], f4 = wp[5*j+4];
            const float xa = xr[2*j], xb = xr[2*j+1];
            dot[0]=fmaf(xa,f0.x,dot[0]); dot[1]=fmaf(xa,f0.y,dot[1]);
            dot[2]=fmaf(xa,f0.z,dot[2]); dot[3]=fmaf(xa,f0.w,dot[3]);
            dot[4]=fmaf(xa,f1.x,dot[4]); dot[5]=fmaf(xa,f1.y,dot[5]);
            dot[6]=fmaf(xa,f1.z,dot[6]); dot[7]=fmaf(xa,f1.w,dot[7]);
            dot[8]=fmaf(xa,f2.x,dot[8]); dot[9]=fmaf(xa,f2.y,dot[9]);
            dot[0]=fmaf(xb,f2.z,dot[0]); dot[1]=fmaf(xb,f2.w,dot[1]);
            dot[2]=fmaf(xb,f3.x,dot[2]); dot[3]=fmaf(xb,f3.y,dot[3]);
            dot[4]=fmaf(xb,f3.z,dot[4]); dot[5]=fmaf(xb,f3.w,dot[5]);
            dot[6]=fmaf(xb,f4.x,dot[6]); dot[7]=fmaf(xb,f4.y,dot[7]);
            dot[8]=fmaf(xb,f4.z,dot[8]); dot[9]=fmaf(xb,f4.w,dot[9]);
        }
    }
    #pragma unroll
    for (int w = 0; w < NQ; ++w) dot[w] = red16(dot[w]);

    float u0[NQ], u1[NQ];
    #pragma unroll
    for (int w = 0; w < NQ; ++w) {
        const float th2 = tanhf(dot[w] + b1[w]) * 0.78539816339744830962f;  // pi/4
        float s, c;
        sincosf(th2, &s, &c);
        const float isq2 = 0.70710678118654752440f;
        u0[w] = (c - s) * isq2;
        u1[w] = (c + s) * isq2;
    }

    // ---------- initial product state with E_0 folded (bit relabel) ----------
    // w1 <- b2^b3, w3 <- b0^b1 (lane); w5 <- m3^m4, w7 <- m1^m2, w9 <- comp^m0
    v2f A[32];
    {
        float lf = ((lane16 & 8) ? u1[0] : u0[0]);
        lf *= ((((lane16 >> 2) ^ (lane16 >> 3)) & 1) ? u1[1] : u0[1]);
        lf *= ((lane16 & 2) ? u1[2] : u0[2]);
        lf *= (((lane16 ^ (lane16 >> 1)) & 1) ? u1[3] : u0[3]);
        #pragma unroll
        for (int m = 0; m < 32; ++m) {
            float f = ((m & 16) ? u1[4] : u0[4]);
            f *= ((((m >> 3) ^ (m >> 4)) & 1) ? u1[5] : u0[5]);
            f *= ((m & 4) ? u1[6] : u0[6]);
            f *= ((((m >> 1) ^ (m >> 2)) & 1) ? u1[7] : u0[7]);
            f *= ((m & 1) ? u1[8] : u0[8]);
            f *= lf;
            A[m] = (m & 1) ? mk(f * u1[9], f * u0[9]) : mk(f * u0[9], f * u1[9]);
        }
    }

    __syncthreads();  // csl ready

    // ---------- 6 fused layers ----------
    #pragma unroll 1
    for (int k = 0; k < QD; ++k) {
        const float4* cp = (const float4*)(csl + k * 2 * NQ);
        const float4 g0 = cp[0], g1 = cp[1], g2 = cp[2], g3 = cp[3], g4 = cp[4];
        const float C0=g0.x,S0=g0.y, C1=g0.z,S1=g0.w;
        const float C2=g1.x,S2=g1.y, C3=g1.z,S3=g1.w;
        const float C4=g2.x,S4=g2.y, C5=g2.z,S5=g2.w;
        const float C6=g3.x,S6=g3.y, C7=g3.z,S7=g3.w;
        const float C8=g4.x,S8=g4.y, C9=g4.z,S9=g4.w;
        const bool fuse = (k < QD - 1);

        // ==== even phase ====
        {   // w0 plain: t = lane b3 (xor8 via row_ror:8)
            const float g = (lane16 & 8) ? S0 : -S0;
            const v2f al = sp(C0), be = sp(g);
            #pragma unroll
            for (int m = 0; m < 32; ++m) { const v2f p = sx2<8>(A[m]); A[m] = PKF(al, A[m], be * p); }
        }
        {   // w2 + pre C(1,2): t = lane b1 (quad_perm), c = lane b2
            const float g = (lane16 & 2) ? S2 : -S2;
            const bool cb = (lane16 & 4) != 0;
            const v2f al = sp(cb ? g : C2), be = sp(cb ? C2 : g);
            #pragma unroll
            for (int m = 0; m < 32; ++m) { const v2f p = sx2<2>(A[m]); A[m] = PKF(al, A[m], be * p); }
        }
        {   // w4 + pre C(3,4): t = m4 (pairs m, m+16), c = lane b0
            const bool cb = (lane16 & 1) != 0;
            const v2f a0 = sp(cb ? -S4 : C4), b0 = sp(cb ? C4 : -S4);
            const v2f a1 = sp(cb ?  S4 : C4), b1v = sp(cb ? C4 :  S4);
            #pragma unroll
            for (int m = 0; m < 16; ++m) {
                const v2f lo = A[m], hi = A[m + 16];
                A[m]      = PKF(a0, lo, b0 * hi);
                A[m + 16] = PKF(a1, hi, b1v * lo);
            }
        }
        {   // w6 + pre C(5,6): t = m2 (pairs m, m+4), c = m3 (compile-time)
            #pragma unroll
            for (int m = 0; m < 32; ++m) {
                if (m & 4) continue;
                const v2f lo = A[m], hi = A[m + 4];
                if ((m >> 3) & 1) {
                    A[m]     = PKF(sp(-S6), lo, sp(C6) * hi);
                    A[m + 4] = PKF(sp( S6), hi, sp(C6) * lo);
                } else {
                    A[m]     = PKF(sp(C6), lo, sp(-S6) * hi);
                    A[m + 4] = PKF(sp(C6), hi, sp( S6) * lo);
                }
            }
        }
        {   // w8 + pre C(7,8): t = m0 (pairs 2q, 2q+1), c = m1 (compile-time)
            #pragma unroll
            for (int q = 0; q < 16; ++q) {
                const v2f lo = A[2*q], hi = A[2*q+1];
                if (q & 1) {
                    A[2*q]   = PKF(sp(-S8), lo, sp(C8) * hi);
                    A[2*q+1] = PKF(sp( S8), hi, sp(C8) * lo);
                } else {
                    A[2*q]   = PKF(sp(C8), lo, sp(-S8) * hi);
                    A[2*q+1] = PKF(sp(C8), hi, sp( S8) * lo);
                }
            }
        }

        // ==== odd phase ====
        {   // w1 + post C(0,1): t = lane b2 (xor4 via dual DPP), c = lane b3
            const float g = (lane16 & 4) ? S1 : -S1;
            const bool cb = fuse && ((lane16 & 8) != 0);
            const v2f al = sp(cb ? -g : C1), be = sp(cb ? C1 : g);
            #pragma unroll
            for (int m = 0; m < 32; ++m) { const v2f p = sx2<4>(A[m]); A[m] = PKF(al, A[m], be * p); }
        }
        {   // w3 + post C(2,3): t = lane b0 (quad_perm), c = lane b1
            const float g = (lane16 & 1) ? S3 : -S3;
            const bool cb = fuse && ((lane16 & 2) != 0);
            const v2f al = sp(cb ? -g : C3), be = sp(cb ? C3 : g);
            #pragma unroll
            for (int m = 0; m < 32; ++m) { const v2f p = sx2<1>(A[m]); A[m] = PKF(al, A[m], be * p); }
        }
        {   // w5 + post C(4,5): t = m3 (pairs m, m+8), c = m4
            const float a0c = fuse ?  S5 : C5,  b0c = fuse ? C5 : -S5;
            const float a1c = fuse ? -S5 : C5,  b1c = fuse ? C5 :  S5;
            #pragma unroll
            for (int m = 0; m < 32; ++m) {
                if (m & 8) continue;
                const v2f lo = A[m], hi = A[m + 8];
                if ((m >> 4) & 1) {
                    A[m]     = PKF(sp(a0c), lo, sp(b0c) * hi);
                    A[m + 8] = PKF(sp(a1c), hi, sp(b1c) * lo);
                } else {
                    A[m]     = PKF(sp(C5), lo, sp(-S5) * hi);
                    A[m + 8] = PKF(sp(C5), hi, sp( S5) * lo);
                }
            }
        }
        {   // w7 + post C(6,7): t = m1 (pairs m, m+2), c = m2
            const float a0c = fuse ?  S7 : C7,  b0c = fuse ? C7 : -S7;
            const float a1c = fuse ? -S7 : C7,  b1c = fuse ? C7 :  S7;
            #pragma unroll
            for (int m = 0; m < 32; ++m) {
                if (m & 2) continue;
                const v2f lo = A[m], hi = A[m + 2];
                if ((m >> 2) & 1) {
                    A[m]     = PKF(sp(a0c), lo, sp(b0c) * hi);
                    A[m + 2] = PKF(sp(a1c), hi, sp(b1c) * lo);
                } else {
                    A[m]     = PKF(sp(C7), lo, sp(-S7) * hi);
                    A[m + 2] = PKF(sp(C7), hi, sp( S7) * lo);
                }
            }
        }
        {   // w9 + post C(8,9): t = comp (in-register pair), c = m0
            const v2f Ae = sp(C9), Be = mk(-S9, S9);
            const v2f Ao = fuse ? mk(S9, -S9) : Ae;
            const v2f Bo = fuse ? sp(C9) : Be;
            #pragma unroll
            for (int m = 0; m < 32; ++m) {
                const v2f s = mk(A[m].y, A[m].x);
                A[m] = (m & 1) ? PKF(Ao, A[m], Bo * s) : PKF(Ae, A[m], Be * s);
            }
        }
    }

    // ---------- expvals <Z_w> ----------
    v2f tot2 = sp(0.f), q4 = sp(0.f), q5 = sp(0.f), q6 = sp(0.f), q7 = sp(0.f), q8 = sp(0.f);
    #pragma unroll
    for (int m = 0; m < 32; ++m) {
        const v2f P = A[m] * A[m];
        tot2 += P;
        if (m & 16) q4 += P;
        if (m & 8)  q5 += P;
        if (m & 4)  q6 += P;
        if (m & 2)  q7 += P;
        if (m & 1)  q8 += P;
    }
    const float tot = tot2.x + tot2.y;
    float e[NQ];
    e[0] = (lane16 & 8) ? -tot : tot;
    e[1] = (lane16 & 4) ? -tot : tot;
    e[2] = (lane16 & 2) ? -tot : tot;
    e[3] = (lane16 & 1) ? -tot : tot;
    e[4] = tot - 2.f * (q4.x + q4.y);
    e[5] = tot - 2.f * (q5.x + q5.y);
    e[6] = tot - 2.f * (q6.x + q6.y);
    e[7] = tot - 2.f * (q7.x + q7.y);
    e[8] = tot - 2.f * (q8.x + q8.y);
    e[9] = tot - 2.f * tot2.y;
    #pragma unroll
    for (int w = 0; w < NQ; ++w) e[w] = red16(e[w]);

    // ---------- output GEMM ----------
    if (b < B) {
        float4 o = ((const float4*)b2)[lane16];
        #pragma unroll
        for (int w = 0; w < NQ; ++w) {
            const float4 wv = ((const float4*)(W2 + w * DOUT))[lane16];
            o.x = fmaf(e[w], wv.x, o.x);
            o.y = fmaf(e[w], wv.y, o.y);
            o.z = fmaf(e[w], wv.z, o.z);
            o.w = fmaf(e[w], wv.w, o.w);
        }
        ((float4*)(out + (size_t)b * DOUT))[lane16] = o;
    }
}

extern "C" void kernel_launch(void* const* d_in, const int* in_sizes, int n_in,
                              void* d_out, int out_size, void* d_ws, size_t ws_size,
                              hipStream_t stream) {
    const float* x  = (const float*)d_in[0];
    const float* W1 = (const float*)d_in[1];
    const float* b1 = (const float*)d_in[2];
    const float* qw = (const float*)d_in[3];
    const float* W2 = (const float*)d_in[4];
    const float* b2 = (const float*)d_in[5];
    float* out = (float*)d_out;

    const int B = in_sizes[0] / DIN;
    const int blocks = (B + 15) / 16;
    dqc_main<<<blocks, 256, 0, stream>>>(x, W1, b1, qw, W2, b2, out, B);
}

// Round 5
// 108.601 us; speedup vs baseline: 1.5789x; 1.0280x over previous
//
#include <hip/hip_runtime.h>

#define NQ 10
#define QD 6
#define DIN 512
#define DOUT 64

typedef float v2f __attribute__((ext_vector_type(2)));

__device__ __forceinline__ v2f sp(float s) { v2f r; r.x = s; r.y = s; return r; }
__device__ __forceinline__ v2f mk(float a, float b) { v2f r; r.x = a; r.y = b; return r; }
#define PKF(a, b, c) __builtin_elementwise_fma(a, b, c)

// ---- cross-lane helpers (within 32-lane groups) ------------------------
// xor1 = quad_perm[1,0,3,2] (0xB1)          lane bit0
// xor2 = quad_perm[2,3,0,1] (0x4E)          lane bit1
// xor4 = row_half_mirror(0x141) o quad_perm[3,2,1,0](0x1B)   lane bit2
// xor8 = row_ror:8 (0x128)                  lane bit3
// xor16 = ds_swizzle BitMode (0x401F)       lane bit4 (32-lane groups)
template <int CTRL>
__device__ __forceinline__ float dppf(float v) {
    return __int_as_float(__builtin_amdgcn_mov_dpp(__float_as_int(v), CTRL, 0xF, 0xF, true));
}
template <int M>
__device__ __forceinline__ float sx(float v) {
    if constexpr (M == 1)       return dppf<0xB1>(v);
    else if constexpr (M == 2)  return dppf<0x4E>(v);
    else if constexpr (M == 4)  return dppf<0x1B>(dppf<0x141>(v));
    else if constexpr (M == 8)  return dppf<0x128>(v);
    else return __int_as_float(__builtin_amdgcn_ds_swizzle(__float_as_int(v), 0x401F));
}
template <int M>
__device__ __forceinline__ v2f sx2(v2f v) { return mk(sx<M>(v.x), sx<M>(v.y)); }
// allreduce over 32-lane groups
__device__ __forceinline__ float red32(float v) {
    v += dppf<0x128>(v);   // row_ror:8
    v += dppf<0x124>(v);   // row_ror:4
    v += dppf<0x122>(v);   // row_ror:2
    v += dppf<0x121>(v);   // row_ror:1
    v += sx<16>(v);        // cross-row
    return v;
}

// One 32-lane group = one sample (2 samples/wave -> 4096 waves, 4 waves/SIMD).
// Amp idx = (lane32<<5) | r, r = 2m|comp (m = 0..15, 16 v2f per lane).
// Wires 0..4 = lane32 bits 4..0; wires 5..9 = m3,m2,m1,m0,comp.
// CNOTs fused into RY coefficient tables:
//   pre-CNOT+RY : (al,be) = cbit ? ( g, C) : (C, g),  g = tbit ? S : -S
//   RY+post-CNOT: (al,be) = cbit ? (-g, C) : (C, g)
// Layer = O_k * R_k * E_{k+1}; E_0 folded into initial state (bit relabel).
__global__ __launch_bounds__(256, 4) void dqc_main(
    const float* __restrict__ x,
    const float* __restrict__ W1,
    const float* __restrict__ b1,
    const float* __restrict__ qw,
    const float* __restrict__ W2,
    const float* __restrict__ b2,
    float* __restrict__ out,
    const int B)
{
    __shared__ __align__(16) float csl[2 * QD * NQ];

    const int tid = threadIdx.x;
    if (tid < QD * NQ) {
        float s, c;
        sincosf(qw[tid] * 0.5f, &s, &c);
        csl[2 * tid] = c; csl[2 * tid + 1] = s;
    }

    const int lane32 = tid & 31;
    const int b  = (blockIdx.x * 256 + tid) >> 5;
    const int bb = (b < B) ? b : (B - 1);

    // ---------- front-end: dot = x[b,:] @ W1 ----------
    float xr[16];
    {
        const float4* xp = (const float4*)(x + (size_t)bb * DIN + lane32 * 16);
        #pragma unroll
        for (int i = 0; i < 4; ++i) {
            const float4 v = xp[i];
            xr[4*i] = v.x; xr[4*i+1] = v.y; xr[4*i+2] = v.z; xr[4*i+3] = v.w;
        }
    }
    float dot[NQ];
    #pragma unroll
    for (int w = 0; w < NQ; ++w) dot[w] = 0.f;
    {
        // lane handles W1 rows [16*lane32, +16); 2 rows = 20 floats = 5 float4
        const float4* wp = (const float4*)(W1 + (size_t)lane32 * 16 * NQ);
        #pragma unroll
        for (int j = 0; j < 8; ++j) {
            const float4 f0 = wp[5*j], f1 = wp[5*j+1], f2 = wp[5*j+2],
                         f3 = wp[5*j+3], f4 = wp[5*j+4];
            const float xa = xr[2*j], xb = xr[2*j+1];
            dot[0]=fmaf(xa,f0.x,dot[0]); dot[1]=fmaf(xa,f0.y,dot[1]);
            dot[2]=fmaf(xa,f0.z,dot[2]); dot[3]=fmaf(xa,f0.w,dot[3]);
            dot[4]=fmaf(xa,f1.x,dot[4]); dot[5]=fmaf(xa,f1.y,dot[5]);
            dot[6]=fmaf(xa,f1.z,dot[6]); dot[7]=fmaf(xa,f1.w,dot[7]);
            dot[8]=fmaf(xa,f2.x,dot[8]); dot[9]=fmaf(xa,f2.y,dot[9]);
            dot[0]=fmaf(xb,f2.z,dot[0]); dot[1]=fmaf(xb,f2.w,dot[1]);
            dot[2]=fmaf(xb,f3.x,dot[2]); dot[3]=fmaf(xb,f3.y,dot[3]);
            dot[4]=fmaf(xb,f3.z,dot[4]); dot[5]=fmaf(xb,f3.w,dot[5]);
            dot[6]=fmaf(xb,f4.x,dot[6]); dot[7]=fmaf(xb,f4.y,dot[7]);
            dot[8]=fmaf(xb,f4.z,dot[8]); dot[9]=fmaf(xb,f4.w,dot[9]);
        }
    }
    #pragma unroll
    for (int w = 0; w < NQ; ++w) dot[w] = red32(dot[w]);

    float u0[NQ], u1[NQ];
    #pragma unroll
    for (int w = 0; w < NQ; ++w) {
        const float th2 = tanhf(dot[w] + b1[w]) * 0.78539816339744830962f;  // pi/4
        float s, c;
        sincosf(th2, &s, &c);
        const float isq2 = 0.70710678118654752440f;
        u0[w] = (c - s) * isq2;
        u1[w] = (c + s) * isq2;
    }

    // ---------- initial product state with E_0 folded (bit relabel) ----------
    // f0@b4, f1@b3^b4, f2@b2, f3@b1^b2, f4@b0 (lane bits);
    // f5@m3^b0 (!), f6@m2, f7@m1^m2, f8@m0, f9@comp^m0
    v2f A[16];
    {
        float lf = ((lane32 & 16) ? u1[0] : u0[0]);
        lf *= ((((lane32 >> 3) ^ (lane32 >> 4)) & 1) ? u1[1] : u0[1]);
        lf *= ((lane32 & 4) ? u1[2] : u0[2]);
        lf *= ((((lane32 >> 1) ^ (lane32 >> 2)) & 1) ? u1[3] : u0[3]);
        lf *= ((lane32 & 1) ? u1[4] : u0[4]);
        const bool b0 = (lane32 & 1) != 0;
        const float w5a = b0 ? u1[5] : u0[5];   // m3 = 0
        const float w5b = b0 ? u0[5] : u1[5];   // m3 = 1
        #pragma unroll
        for (int m = 0; m < 16; ++m) {
            float f = ((m & 8) ? w5b : w5a);
            f *= ((m & 4) ? u1[6] : u0[6]);
            f *= ((((m >> 1) ^ (m >> 2)) & 1) ? u1[7] : u0[7]);
            f *= ((m & 1) ? u1[8] : u0[8]);
            f *= lf;
            A[m] = (m & 1) ? mk(f * u1[9], f * u0[9]) : mk(f * u0[9], f * u1[9]);
        }
    }

    __syncthreads();  // csl ready

    // ---------- 6 fused layers ----------
    #pragma unroll 1
    for (int k = 0; k < QD; ++k) {
        const float4* cp = (const float4*)(csl + k * 2 * NQ);
        const float4 g0 = cp[0], g1 = cp[1], g2 = cp[2], g3 = cp[3], g4 = cp[4];
        const float C0=g0.x,S0=g0.y, C1=g0.z,S1=g0.w;
        const float C2=g1.x,S2=g1.y, C3=g1.z,S3=g1.w;
        const float C4=g2.x,S4=g2.y, C5=g2.z,S5=g2.w;
        const float C6=g3.x,S6=g3.y, C7=g3.z,S7=g3.w;
        const float C8=g4.x,S8=g4.y, C9=g4.z,S9=g4.w;
        const bool fuse = (k < QD - 1);

        // ==== even phase ====
        {   // w0 plain: t = lane b4 (ds_swizzle xor16)
            const float g = (lane32 & 16) ? S0 : -S0;
            const v2f al = sp(C0), be = sp(g);
            #pragma unroll
            for (int m = 0; m < 16; ++m) { const v2f p = sx2<16>(A[m]); A[m] = PKF(al, A[m], be * p); }
        }
        {   // w2 + pre C(1,2): t = lane b2 (xor4 dual-DPP), c = lane b3
            const float g = (lane32 & 4) ? S2 : -S2;
            const bool cb = (lane32 & 8) != 0;
            const v2f al = sp(cb ? g : C2), be = sp(cb ? C2 : g);
            #pragma unroll
            for (int m = 0; m < 16; ++m) { const v2f p = sx2<4>(A[m]); A[m] = PKF(al, A[m], be * p); }
        }
        {   // w4 + pre C(3,4): t = lane b0 (xor1 quad_perm), c = lane b1
            const float g = (lane32 & 1) ? S4 : -S4;
            const bool cb = (lane32 & 2) != 0;
            const v2f al = sp(cb ? g : C4), be = sp(cb ? C4 : g);
            #pragma unroll
            for (int m = 0; m < 16; ++m) { const v2f p = sx2<1>(A[m]); A[m] = PKF(al, A[m], be * p); }
        }
        {   // w6 + pre C(5,6): t = m2 (pairs m, m+4), c = m3 (compile-time)
            #pragma unroll
            for (int m = 0; m < 16; ++m) {
                if (m & 4) continue;
                const v2f lo = A[m], hi = A[m + 4];
                if ((m >> 3) & 1) {
                    A[m]     = PKF(sp(-S6), lo, sp(C6) * hi);
                    A[m + 4] = PKF(sp( S6), hi, sp(C6) * lo);
                } else {
                    A[m]     = PKF(sp(C6), lo, sp(-S6) * hi);
                    A[m + 4] = PKF(sp(C6), hi, sp( S6) * lo);
                }
            }
        }
        {   // w8 + pre C(7,8): t = m0 (pairs m, m+1), c = m1 (compile-time)
            #pragma unroll
            for (int m = 0; m < 16; m += 2) {
                const v2f lo = A[m], hi = A[m + 1];
                if ((m >> 1) & 1) {
                    A[m]     = PKF(sp(-S8), lo, sp(C8) * hi);
                    A[m + 1] = PKF(sp( S8), hi, sp(C8) * lo);
                } else {
                    A[m]     = PKF(sp(C8), lo, sp(-S8) * hi);
                    A[m + 1] = PKF(sp(C8), hi, sp( S8) * lo);
                }
            }
        }

        // ==== odd phase ====
        {   // w1 + post C(0,1): t = lane b3 (xor8 row_ror), c = lane b4
            const float g = (lane32 & 8) ? S1 : -S1;
            const bool cb = fuse && ((lane32 & 16) != 0);
            const v2f al = sp(cb ? -g : C1), be = sp(cb ? C1 : g);
            #pragma unroll
            for (int m = 0; m < 16; ++m) { const v2f p = sx2<8>(A[m]); A[m] = PKF(al, A[m], be * p); }
        }
        {   // w3 + post C(2,3): t = lane b1 (xor2 quad_perm), c = lane b2
            const float g = (lane32 & 2) ? S3 : -S3;
            const bool cb = fuse && ((lane32 & 4) != 0);
            const v2f al = sp(cb ? -g : C3), be = sp(cb ? C3 : g);
            #pragma unroll
            for (int m = 0; m < 16; ++m) { const v2f p = sx2<2>(A[m]); A[m] = PKF(al, A[m], be * p); }
        }
        {   // w5 + post C(4,5): t = m3 (pairs m, m+8), c = lane b0 (runtime)
            const bool cb = fuse && ((lane32 & 1) != 0);
            const v2f a_lo = sp(cb ?  S5 : C5), b_lo = sp(cb ? C5 : -S5);
            const v2f a_hi = sp(cb ? -S5 : C5), b_hi = sp(cb ? C5 :  S5);
            #pragma unroll
            for (int m = 0; m < 8; ++m) {
                const v2f lo = A[m], hi = A[m + 8];
                A[m]     = PKF(a_lo, lo, b_lo * hi);
                A[m + 8] = PKF(a_hi, hi, b_hi * lo);
            }
        }
        {   // w7 + post C(6,7): t = m1 (pairs m, m+2), c = m2 (compile-time + fuse)
            #pragma unroll
            for (int m = 0; m < 16; ++m) {
                if (m & 2) continue;
                const v2f lo = A[m], hi = A[m + 2];
                if (fuse && ((m >> 2) & 1)) {
                    A[m]     = PKF(sp( S7), lo, sp(C7) * hi);
                    A[m + 2] = PKF(sp(-S7), hi, sp(C7) * lo);
                } else {
                    A[m]     = PKF(sp(C7), lo, sp(-S7) * hi);
                    A[m + 2] = PKF(sp(C7), hi, sp( S7) * lo);
                }
            }
        }
        {   // w9 + post C(8,9): t = comp (in-register pair), c = m0 (compile-time + fuse)
            const v2f Ae = sp(C9), Be = mk(-S9, S9);
            const v2f Ao = fuse ? mk(S9, -S9) : Ae;
            const v2f Bo = fuse ? sp(C9) : Be;
            #pragma unroll
            for (int m = 0; m < 16; ++m) {
                const v2f s = mk(A[m].y, A[m].x);
                A[m] = (m & 1) ? PKF(Ao, A[m], Bo * s) : PKF(Ae, A[m], Be * s);
            }
        }
    }

    // ---------- expvals <Z_w> ----------
    v2f tot2 = sp(0.f), q5 = sp(0.f), q6 = sp(0.f), q7 = sp(0.f), q8 = sp(0.f);
    #pragma unroll
    for (int m = 0; m < 16; ++m) {
        const v2f P = A[m] * A[m];
        tot2 += P;
        if (m & 8) q5 += P;
        if (m & 4) q6 += P;
        if (m & 2) q7 += P;
        if (m & 1) q8 += P;
    }
    const float tot = tot2.x + tot2.y;
    float e[NQ];
    e[0] = (lane32 & 16) ? -tot : tot;
    e[1] = (lane32 & 8)  ? -tot : tot;
    e[2] = (lane32 & 4)  ? -tot : tot;
    e[3] = (lane32 & 2)  ? -tot : tot;
    e[4] = (lane32 & 1)  ? -tot : tot;
    e[5] = tot - 2.f * (q5.x + q5.y);
    e[6] = tot - 2.f * (q6.x + q6.y);
    e[7] = tot - 2.f * (q7.x + q7.y);
    e[8] = tot - 2.f * (q8.x + q8.y);
    e[9] = tot - 2.f * tot2.y;
    #pragma unroll
    for (int w = 0; w < NQ; ++w) e[w] = red32(e[w]);

    // ---------- output GEMM: lane covers cols [2*lane32, +2) ----------
    if (b < B) {
        float2 o = ((const float2*)b2)[lane32];
        #pragma unroll
        for (int w = 0; w < NQ; ++w) {
            const float2 wv = ((const float2*)(W2 + w * DOUT))[lane32];
            o.x = fmaf(e[w], wv.x, o.x);
            o.y = fmaf(e[w], wv.y, o.y);
        }
        ((float2*)(out + (size_t)b * DOUT))[lane32] = o;
    }
}

extern "C" void kernel_launch(void* const* d_in, const int* in_sizes, int n_in,
                              void* d_out, int out_size, void* d_ws, size_t ws_size,
                              hipStream_t stream) {
    const float* x  = (const float*)d_in[0];
    const float* W1 = (const float*)d_in[1];
    const float* b1 = (const float*)d_in[2];
    const float* qw = (const float*)d_in[3];
    const float* W2 = (const float*)d_in[4];
    const float* b2 = (const float*)d_in[5];
    float* out = (float*)d_out;

    const int B = in_sizes[0] / DIN;
    const int blocks = (B + 7) / 8;   // 8 samples per 256-thread block
    dqc_main<<<blocks, 256, 0, stream>>>(x, W1, b1, qw, W2, b2, out, B);
}

// Round 6
// 106.171 us; speedup vs baseline: 1.6151x; 1.0229x over previous
//
#include <hip/hip_runtime.h>

#define NQ 10
#define QD 6
#define DIN 512
#define DOUT 64

typedef float v2f __attribute__((ext_vector_type(2)));

__device__ __forceinline__ v2f sp(float s) { v2f r; r.x = s; r.y = s; return r; }
__device__ __forceinline__ v2f mk(float a, float b) { v2f r; r.x = a; r.y = b; return r; }

// ---- forced packed-fp32 (VOP3P) ops -----------------------------------
__device__ __forceinline__ v2f pk_fma(v2f a, v2f b, v2f c) {
    v2f d; asm("v_pk_fma_f32 %0, %1, %2, %3" : "=v"(d) : "v"(a), "v"(b), "v"(c)); return d;
}
__device__ __forceinline__ v2f pk_mul(v2f a, v2f b) {
    v2f d; asm("v_pk_mul_f32 %0, %1, %2" : "=v"(d) : "v"(a), "v"(b)); return d;
}
__device__ __forceinline__ v2f pk_add(v2f a, v2f b) {
    v2f d; asm("v_pk_add_f32 %0, %1, %2" : "=v"(d) : "v"(a), "v"(b)); return d;
}

// ---- cross-lane helpers -------------------------------------------------
// xor1=quad_perm[1,0,3,2]; xor2=quad_perm[2,3,0,1]; xor4=row_half_mirror o
// quad_perm[3,2,1,0]; xor8=row_ror:8; xor16=ds_swizzle; xor32=ds_bpermute.
template <int CTRL>
__device__ __forceinline__ float dppf(float v) {
    return __int_as_float(__builtin_amdgcn_mov_dpp(__float_as_int(v), CTRL, 0xF, 0xF, true));
}
template <int M>
__device__ __forceinline__ float sx(float v) {
    if constexpr (M == 1)       return dppf<0xB1>(v);
    else if constexpr (M == 2)  return dppf<0x4E>(v);
    else if constexpr (M == 4)  return dppf<0x1B>(dppf<0x141>(v));
    else if constexpr (M == 8)  return dppf<0x128>(v);
    else                        return __int_as_float(__builtin_amdgcn_ds_swizzle(__float_as_int(v), 0x401F));
}
__device__ __forceinline__ float sx32(float v, int xaddr) {
    return __int_as_float(__builtin_amdgcn_ds_bpermute(xaddr, __float_as_int(v)));
}
template <int M>
__device__ __forceinline__ v2f sx2(v2f v) { return mk(sx<M>(v.x), sx<M>(v.y)); }
__device__ __forceinline__ float red64(float v, int xaddr) {
    v += dppf<0x128>(v);   // row_ror:8
    v += dppf<0x124>(v);   // row_ror:4
    v += dppf<0x122>(v);   // row_ror:2
    v += dppf<0x121>(v);   // row_ror:1
    v += __int_as_float(__builtin_amdgcn_ds_swizzle(__float_as_int(v), 0x401F));
    v += sx32(v, xaddr);
    return v;
}

// One wave64 = one sample. Amp idx = (lane<<4) | (m<<1) | comp, m = 0..7.
// Wires 0..5 = lane bits 5..0; wires 6,7,8 = m bits 2,1,0; wire 9 = comp.
// CNOT fusion (as R4/R5, re-mapped):
//   pre-CNOT+RY : (al,be) = cbit ? ( g, C) : (C, g),  g = tbit ? S : -S
//   RY+post-CNOT: (al,be) = cbit ? (-g, C) : (C, g)
// Even phase: w0, w2+preC12, w4+preC34, w6+preC56, w8+preC78
// Odd  phase: w1+postC01, w3+postC23, w5+postC45, w7+postC67, w9+postC89
// E_0 folded into initial state (bit relabel).
__global__ __launch_bounds__(256, 8) void dqc_main(
    const float* __restrict__ x,
    const float* __restrict__ W1,
    const float* __restrict__ b1,
    const float* __restrict__ qw,
    const float* __restrict__ W2,
    const float* __restrict__ b2,
    float* __restrict__ out,
    const int B)
{
    // per layer (stride 24 floats for b128 alignment):
    // [C0,S0,C2,S2,C4,S4,C6,S6,C8,S8, pad2, C1,S1,C3,S3,C5,S5,C7,S7,C9,S9, pad2]
    __shared__ __align__(16) float csl[QD * 24];

    const int tid = threadIdx.x;
    if (tid < QD * NQ) {
        const int layer = tid / NQ, wire = tid - layer * NQ;
        float s, c;
        sincosf(qw[tid] * 0.5f, &s, &c);
        const int pos = layer * 24 + (wire & 1) * 12 + (wire >> 1) * 2;
        csl[pos] = c; csl[pos + 1] = s;
    }

    const int lane = tid & 63;
    const int b = blockIdx.x * 4 + (tid >> 6);
    const int bb = (b < B) ? b : (B - 1);
    const int xaddr = ((tid ^ 32) & 63) << 2;   // bpermute addr: lane^32

    // ---------- front-end: dot = x[b,:] @ W1 ----------
    float xr[8];
    {
        const float4* xp = (const float4*)(x + (size_t)bb * DIN + lane * 8);
        const float4 v0 = xp[0], v1 = xp[1];
        xr[0]=v0.x; xr[1]=v0.y; xr[2]=v0.z; xr[3]=v0.w;
        xr[4]=v1.x; xr[5]=v1.y; xr[6]=v1.z; xr[7]=v1.w;
    }
    float dot[NQ];
    #pragma unroll
    for (int w = 0; w < NQ; ++w) dot[w] = 0.f;
    {
        // lane handles W1 rows [8*lane, +8); 2 rows = 20 floats = 5 float4
        const float4* wp = (const float4*)(W1 + (size_t)lane * 8 * NQ);
        #pragma unroll
        for (int j = 0; j < 4; ++j) {
            const float4 f0 = wp[5*j], f1 = wp[5*j+1], f2 = wp[5*j+2],
                         f3 = wp[5*j+3], f4 = wp[5*j+4];
            const float xa = xr[2*j], xb = xr[2*j+1];
            dot[0]=fmaf(xa,f0.x,dot[0]); dot[1]=fmaf(xa,f0.y,dot[1]);
            dot[2]=fmaf(xa,f0.z,dot[2]); dot[3]=fmaf(xa,f0.w,dot[3]);
            dot[4]=fmaf(xa,f1.x,dot[4]); dot[5]=fmaf(xa,f1.y,dot[5]);
            dot[6]=fmaf(xa,f1.z,dot[6]); dot[7]=fmaf(xa,f1.w,dot[7]);
            dot[8]=fmaf(xa,f2.x,dot[8]); dot[9]=fmaf(xa,f2.y,dot[9]);
            dot[0]=fmaf(xb,f2.z,dot[0]); dot[1]=fmaf(xb,f2.w,dot[1]);
            dot[2]=fmaf(xb,f3.x,dot[2]); dot[3]=fmaf(xb,f3.y,dot[3]);
            dot[4]=fmaf(xb,f3.z,dot[4]); dot[5]=fmaf(xb,f3.w,dot[5]);
            dot[6]=fmaf(xb,f4.x,dot[6]); dot[7]=fmaf(xb,f4.y,dot[7]);
            dot[8]=fmaf(xb,f4.z,dot[8]); dot[9]=fmaf(xb,f4.w,dot[9]);
        }
    }
    #pragma unroll
    for (int w = 0; w < NQ; ++w) dot[w] = red64(dot[w], xaddr);

    float u0[NQ], u1[NQ];
    #pragma unroll
    for (int w = 0; w < NQ; ++w) {
        const float th2 = tanhf(dot[w] + b1[w]) * 0.78539816339744830962f;  // pi/4
        float s, c;
        sincosf(th2, &s, &c);
        const float isq2 = 0.70710678118654752440f;
        u0[w] = (c - s) * isq2;
        u1[w] = (c + s) * isq2;
    }

    // ---------- initial product state with E_0 folded (bit relabel) ----------
    // w0@b5, w1@b4^b5, w2@b3, w3@b2^b3, w4@b1, w5@b0^b1,
    // w6@m2, w7@m1^m2, w8@m0, w9@comp^m0
    v2f A[8];
    {
        float lf = ((lane & 32) ? u1[0] : u0[0]);
        lf *= ((((lane >> 4) ^ (lane >> 5)) & 1) ? u1[1] : u0[1]);
        lf *= ((lane & 8) ? u1[2] : u0[2]);
        lf *= ((((lane >> 2) ^ (lane >> 3)) & 1) ? u1[3] : u0[3]);
        lf *= ((lane & 2) ? u1[4] : u0[4]);
        lf *= (((lane ^ (lane >> 1)) & 1) ? u1[5] : u0[5]);
        #pragma unroll
        for (int m = 0; m < 8; ++m) {
            float f = ((m & 4) ? u1[6] : u0[6]);
            f *= ((((m >> 1) ^ (m >> 2)) & 1) ? u1[7] : u0[7]);
            f *= ((m & 1) ? u1[8] : u0[8]);
            f *= lf;
            A[m] = (m & 1) ? mk(f * u1[9], f * u0[9]) : mk(f * u0[9], f * u1[9]);
        }
    }

    __syncthreads();  // csl ready (no early return above)

    // ---------- 6 fused layers ----------
    #pragma unroll 1
    for (int k = 0; k < QD; ++k) {
        const float* ce = csl + k * 24;
        const bool fuse = (k != QD - 1);

        const float4 ea = *(const float4*)(ce);
        const float4 eb = *(const float4*)(ce + 4);
        const float2 ec = *(const float2*)(ce + 8);
        const float C0=ea.x, S0=ea.y, C2=ea.z, S2=ea.w;
        const float C4=eb.x, S4=eb.y, C6=eb.z, S6=eb.w;
        const float C8=ec.x, S8=ec.y;

        {   // w0 plain: partner lane^32 (bpermute)
            const float g = (lane & 32) ? S0 : -S0;
            const v2f alv = sp(C0), bev = sp(g);
            #pragma unroll
            for (int m = 0; m < 8; ++m) {
                const v2f p = mk(sx32(A[m].x, xaddr), sx32(A[m].y, xaddr));
                A[m] = pk_fma(alv, A[m], pk_mul(bev, p));
            }
        }
        {   // w2 + pre C(1,2): partner lane^8, ctrl lane b4
            const float g = (lane & 8) ? S2 : -S2;
            const bool cb = (lane & 16) != 0;
            const v2f alv = sp(cb ? g : C2), bev = sp(cb ? C2 : g);
            #pragma unroll
            for (int m = 0; m < 8; ++m) {
                const v2f p = sx2<8>(A[m]);
                A[m] = pk_fma(alv, A[m], pk_mul(bev, p));
            }
        }
        {   // w4 + pre C(3,4): partner lane^2, ctrl lane b2
            const float g = (lane & 2) ? S4 : -S4;
            const bool cb = (lane & 4) != 0;
            const v2f alv = sp(cb ? g : C4), bev = sp(cb ? C4 : g);
            #pragma unroll
            for (int m = 0; m < 8; ++m) {
                const v2f p = sx2<2>(A[m]);
                A[m] = pk_fma(alv, A[m], pk_mul(bev, p));
            }
        }
        {   // w6 + pre C(5,6): reg pairs (m, m+4), ctrl lane b0 (runtime)
            const bool cb = (lane & 1) != 0;
            const v2f a_lo = sp(cb ? -S6 : C6), b_lo = sp(cb ? C6 : -S6);
            const v2f a_hi = sp(cb ?  S6 : C6), b_hi = sp(cb ? C6 :  S6);
            #pragma unroll
            for (int m = 0; m < 4; ++m) {
                const v2f lo = A[m], hi = A[m + 4];
                A[m]     = pk_fma(a_lo, lo, pk_mul(b_lo, hi));
                A[m + 4] = pk_fma(a_hi, hi, pk_mul(b_hi, lo));
            }
        }
        {   // w8 + pre C(7,8): reg pairs (m, m+1) m even, ctrl m1 (compile-time)
            const v2f c8 = sp(C8), s8 = sp(S8), ns8 = sp(-S8);
            #pragma unroll
            for (int m = 0; m < 8; m += 2) {
                const v2f lo = A[m], hi = A[m + 1];
                if (m & 2) {
                    A[m]     = pk_fma(ns8, lo, pk_mul(c8, hi));
                    A[m + 1] = pk_fma(s8,  hi, pk_mul(c8, lo));
                } else {
                    A[m]     = pk_fma(c8, lo, pk_mul(ns8, hi));
                    A[m + 1] = pk_fma(c8, hi, pk_mul(s8,  lo));
                }
            }
        }

        const float4 oa = *(const float4*)(ce + 12);
        const float4 ob = *(const float4*)(ce + 16);
        const float2 oc = *(const float2*)(ce + 20);
        const float C1=oa.x, S1=oa.y, C3=oa.z, S3=oa.w;
        const float C5=ob.x, S5=ob.y, C7=ob.z, S7=ob.w;
        const float C9=oc.x, S9=oc.y;

        {   // w1 + post C(0,1): partner lane^16 (swizzle), ctrl lane b5
            const float g = (lane & 16) ? S1 : -S1;
            const bool cb = fuse && ((lane & 32) != 0);
            const v2f alv = sp(cb ? -g : C1), bev = sp(cb ? C1 : g);
            #pragma unroll
            for (int m = 0; m < 8; ++m) {
                const v2f p = sx2<16>(A[m]);
                A[m] = pk_fma(alv, A[m], pk_mul(bev, p));
            }
        }
        {   // w3 + post C(2,3): partner lane^4 (dual DPP), ctrl lane b3
            const float g = (lane & 4) ? S3 : -S3;
            const bool cb = fuse && ((lane & 8) != 0);
            const v2f alv = sp(cb ? -g : C3), bev = sp(cb ? C3 : g);
            #pragma unroll
            for (int m = 0; m < 8; ++m) {
                const v2f p = sx2<4>(A[m]);
                A[m] = pk_fma(alv, A[m], pk_mul(bev, p));
            }
        }
        {   // w5 + post C(4,5): partner lane^1, ctrl lane b1
            const float g = (lane & 1) ? S5 : -S5;
            const bool cb = fuse && ((lane & 2) != 0);
            const v2f alv = sp(cb ? -g : C5), bev = sp(cb ? C5 : g);
            #pragma unroll
            for (int m = 0; m < 8; ++m) {
                const v2f p = sx2<1>(A[m]);
                A[m] = pk_fma(alv, A[m], pk_mul(bev, p));
            }
        }
        {   // w7 + post C(6,7): reg pairs (m, m+2), ctrl m2 (compile-time + fuse)
            const v2f c7 = sp(C7), s7 = sp(S7), ns7 = sp(-S7);
            const v2f a_lo4 = fuse ? s7 : c7,  b_lo4 = fuse ? c7 : ns7;
            const v2f a_hi4 = fuse ? ns7 : c7, b_hi4 = fuse ? c7 : s7;
            #pragma unroll
            for (int m = 0; m < 2; ++m) {
                {   const v2f lo = A[m], hi = A[m + 2];
                    A[m]     = pk_fma(c7, lo, pk_mul(ns7, hi));
                    A[m + 2] = pk_fma(c7, hi, pk_mul(s7,  lo)); }
                {   const v2f lo = A[m + 4], hi = A[m + 6];
                    A[m + 4] = pk_fma(a_lo4, lo, pk_mul(b_lo4, hi));
                    A[m + 6] = pk_fma(a_hi4, hi, pk_mul(b_hi4, lo)); }
            }
        }
        {   // w9 + post C(8,9): in-v2f pair, ctrl m0 (compile-time + fuse)
            const float nS9 = -S9;
            const float axx = fuse ? S9 : C9,  axy = fuse ? C9 : nS9;
            const float ayy = fuse ? nS9 : C9, ayx = fuse ? C9 : S9;
            #pragma unroll
            for (int m = 0; m < 8; ++m) {
                const float ax = A[m].x, ay = A[m].y;
                if (m & 1) {
                    A[m].x = fmaf(axx, ax, axy * ay);
                    A[m].y = fmaf(ayy, ay, ayx * ax);
                } else {
                    A[m].x = fmaf(C9, ax, nS9 * ay);
                    A[m].y = fmaf(C9, ay, S9  * ax);
                }
            }
        }
    }

    // ---------- expvals <Z_w> ----------
    v2f P[8];
    #pragma unroll
    for (int m = 0; m < 8; ++m) P[m] = pk_mul(A[m], A[m]);
    const v2f s01 = pk_add(P[0], P[1]), s23 = pk_add(P[2], P[3]);
    const v2f s45 = pk_add(P[4], P[5]), s67 = pk_add(P[6], P[7]);
    const v2f q8v = pk_add(pk_add(P[1], P[3]), pk_add(P[5], P[7]));
    const v2f q6v = pk_add(s45, s67);
    const v2f q7v = pk_add(s23, s67);
    const v2f tot2 = pk_add(pk_add(s01, s23), q6v);
    const float tot = tot2.x + tot2.y;

    float e[NQ];
    e[0] = (lane & 32) ? -tot : tot;
    e[1] = (lane & 16) ? -tot : tot;
    e[2] = (lane & 8)  ? -tot : tot;
    e[3] = (lane & 4)  ? -tot : tot;
    e[4] = (lane & 2)  ? -tot : tot;
    e[5] = (lane & 1)  ? -tot : tot;
    e[6] = fmaf(-2.f, q6v.x + q6v.y, tot);
    e[7] = fmaf(-2.f, q7v.x + q7v.y, tot);
    e[8] = fmaf(-2.f, q8v.x + q8v.y, tot);
    e[9] = fmaf(-2.f, tot2.y, tot);
    #pragma unroll
    for (int w = 0; w < NQ; ++w) e[w] = red64(e[w], xaddr);

    // ---------- output GEMM: lane = output column ----------
    if (b < B) {
        float o = b2[lane];
        #pragma unroll
        for (int w = 0; w < NQ; ++w) o = fmaf(e[w], W2[w * DOUT + lane], o);
        out[(size_t)b * DOUT + lane] = o;
    }
}

extern "C" void kernel_launch(void* const* d_in, const int* in_sizes, int n_in,
                              void* d_out, int out_size, void* d_ws, size_t ws_size,
                              hipStream_t stream) {
    const float* x  = (const float*)d_in[0];
    const float* W1 = (const float*)d_in[1];
    const float* b1 = (const float*)d_in[2];
    const float* qw = (const float*)d_in[3];
    const float* W2 = (const float*)d_in[4];
    const float* b2 = (const float*)d_in[5];
    float* out = (float*)d_out;

    const int B = in_sizes[0] / DIN;
    const int blocks = (B + 3) / 4;   // 4 samples (waves) per 256-thread block
    dqc_main<<<blocks, 256, 0, stream>>>(x, W1, b1, qw, W2, b2, out, B);
}